// Round 1
// baseline (795.611 us; speedup 1.0000x reference)
//
#include <hip/hip_runtime.h>

typedef unsigned short ushort_t;
typedef __attribute__((ext_vector_type(8))) short short8;   // 8 bf16 (4 VGPRs)
typedef __attribute__((ext_vector_type(4))) float f32x4;

#define C1 0.0625f                      // sqrt(2/512)
#define C2 0.029462782549439483f        // sqrt(2/2304)
#define C2SQ (2.0f/2304.0f)
#define C3 0.08838834764831845f         // sqrt(2/256)
#define C4 0.04419417382415922f         // sqrt(2/1024)

__device__ __forceinline__ float bf2f(ushort_t u) {
  union { unsigned int i; float f; } v; v.i = ((unsigned int)u) << 16; return v.f;
}
__device__ __forceinline__ ushort_t f2bf(float f) {
  union { float f; unsigned int i; } v; v.f = f;
  unsigned int r = v.i + 0x7fffu + ((v.i >> 16) & 1u);   // RNE
  return (ushort_t)(r >> 16);
}
__device__ __forceinline__ void async16(const void* g, void* l) {
  __builtin_amdgcn_global_load_lds(
      (const __attribute__((address_space(1))) unsigned int*)g,
      (__attribute__((address_space(3))) unsigned int*)l, 16, 0, 0);
}
__device__ __forceinline__ float lrelu(float v) { return v > 0.f ? v : 0.2f * v; }

// ---------------- prep: style vector s[b][i] (f32 in, f32 out) ----------------
__global__ void k_style(const float* __restrict__ latent, const float* __restrict__ stdW,
                        const float* __restrict__ stdb, float* __restrict__ s) {
  __shared__ float red[256];
  int b = blockIdx.x, ic = blockIdx.y;
  int il = threadIdx.x & 31, lp = threadIdx.x >> 5;
  int i = (ic << 5) + il;
  float acc = 0.f;
  int l0 = lp << 6;
  for (int l = l0; l < l0 + 64; ++l)
    acc += latent[(b << 9) + l] * stdW[(l << 8) + i];
  red[threadIdx.x] = acc;
  __syncthreads();
  if (lp == 0) {
    float v = 0.f;
#pragma unroll
    for (int p = 0; p < 8; ++p) v += red[(p << 5) + il];
    s[(b << 8) + i] = v * C1 + stdb[i];
  }
}

// ---------------- prep: w2[i][o] = c2^2 * sum_tap w^2 ----------------
__global__ void k_w2(const float* __restrict__ convw, float* __restrict__ w2) {
  int t = blockIdx.x * 256 + threadIdx.x;      // i*256+o
  float acc = 0.f;
#pragma unroll
  for (int tap = 0; tap < 9; ++tap) {
    float w = convw[tap * 65536 + t];
    acc += w * w;
  }
  w2[t] = acc * C2SQ;
}

// ---------------- prep: demod d[b][o] ----------------
__global__ void k_demod(const float* __restrict__ w2, const float* __restrict__ s,
                        float* __restrict__ dm) {
  __shared__ float red[256];
  int b = blockIdx.x, oc = blockIdx.y;
  int ol = threadIdx.x & 31, ip = threadIdx.x >> 5;
  int o = (oc << 5) + ol;
  float acc = 0.f;
  int i0 = ip << 5;
  for (int i = i0; i < i0 + 32; ++i) {
    float si = s[(b << 8) + i];
    acc += w2[(i << 8) + o] * si * si;
  }
  red[threadIdx.x] = acc;
  __syncthreads();
  if (ip == 0) {
    float v = 1e-8f;
#pragma unroll
    for (int p = 0; p < 8; ++p) v += red[(p << 5) + ol];
    dm[(b << 8) + o] = rsqrtf(v);
  }
}

// ---------------- prep: conv weights transposed+scaled wt[o][tap*256+i] (bf16) ----------------
__global__ void k_wt(const float* __restrict__ convw, ushort_t* __restrict__ wt) {
  int t = blockIdx.x * 256 + threadIdx.x;      // o*2304 + kk (write-coalesced)
  int o = t / 2304;
  int kk = t - o * 2304;
  int tap = kk >> 8, i = kk & 255;
  wt[t] = f2bf(convw[tap * 65536 + (i << 8) + o] * C2);
}

// ---------------- prep: W1t[n][k] = D1_W[k][n]*c3 ; W2t[o][k] = D2_W[k][o]*c4 (bf16) ----------------
__global__ void k_w1t(const float* __restrict__ d1w, ushort_t* __restrict__ w1t) {
  int t = blockIdx.x * 256 + threadIdx.x;      // n*256 + k
  int n = t >> 8, k = t & 255;
  w1t[t] = f2bf(d1w[(k << 10) + n] * C3);
}
__global__ void k_w2t(const float* __restrict__ d2w, ushort_t* __restrict__ w2t) {
  int t = blockIdx.x * 256 + threadIdx.x;      // o*1024 + k
  int o = t >> 10, k = t & 1023;
  w2t[t] = f2bf(d2w[(k << 8) + o] * C4);
}

// ---------------- prep: modulated + zero-padded input xs[8][130][130][256] (bf16) ----------------
__global__ void k_pad(const float* __restrict__ data, const float* __restrict__ s,
                      ushort_t* __restrict__ xs) {
  int tid = blockIdx.x * 256 + threadIdx.x;    // one thread = 8 channels
  int ci8 = tid & 31;
  int p = tid >> 5;                            // b*130*130 + yp*130 + xp
  int xp = p % 130;
  int q = p / 130;
  int yp = q % 130;
  int b = q / 130;
  short8 ov = {0, 0, 0, 0, 0, 0, 0, 0};
  if (yp >= 1 && yp <= 128 && xp >= 1 && xp <= 128) {
    const f32x4* src = (const f32x4*)(data + ((((b << 7) + (yp - 1)) << 7) + (xp - 1)) * 256 + (ci8 << 3));
    const f32x4* sp  = (const f32x4*)(s + (b << 8) + (ci8 << 3));
    f32x4 v0 = src[0], v1 = src[1];
    f32x4 s0 = sp[0],  s1 = sp[1];
#pragma unroll
    for (int j = 0; j < 4; ++j) ov[j]     = (short)f2bf(v0[j] * s0[j]);
#pragma unroll
    for (int j = 0; j < 4; ++j) ov[4 + j] = (short)f2bf(v1[j] * s1[j]);
  }
  *(short8*)(xs + ((size_t)tid << 3)) = ov;
}

// ---------------- conv3x3 implicit GEMM, BK=64 as two [128][32] half-tiles ----------------
// (row stride stays 64 B -> no new bank conflicts; barrier pairs halved: 72 -> 36/block)
__global__ __launch_bounds__(256) void k_conv(
    const ushort_t* __restrict__ xs, const ushort_t* __restrict__ wt,
    const float* __restrict__ dmod, const float* __restrict__ bias,
    const float* __restrict__ ncoef, const float* __restrict__ noise,
    ushort_t* __restrict__ y) {
  __shared__ __align__(16) ushort_t a_lds[2][128 * 32];   // [half][m][k]
  __shared__ __align__(16) ushort_t b_lds[2][128 * 32];   // [half][n][k]
  int rb = blockIdx.x;                 // b*128 + image row
  int n0 = blockIdx.y << 7;            // cout tile
  int b = rb >> 7, yr = rb & 127;
  int t = threadIdx.x;
  int lane = t & 63;
  int wm = (t >> 7) & 1, wn = (t >> 6) & 1;
  const ushort_t* ximg = xs + (size_t)b * (130 * 130 * 256);

  const f32x4 fz = {0.f, 0.f, 0.f, 0.f};
  f32x4 acc[4][4];
#pragma unroll
  for (int i = 0; i < 4; ++i) {
#pragma unroll
    for (int j = 0; j < 4; ++j) acc[i][j] = fz;
  }

#pragma unroll 1
  for (int tap = 0; tap < 9; ++tap) {
    int ky = tap / 3;
    int kx = tap - ky * 3;
    const ushort_t* arow = ximg + ((yr + ky) * 130 + kx) * 256;   // padded, always in-bounds
#pragma unroll 1
    for (int cp = 0; cp < 4; ++cp) {
#pragma unroll
      for (int h = 0; h < 2; ++h) {
        int k0 = ((cp << 1) + h) << 5;
#pragma unroll
        for (int r = 0; r < 2; ++r) {
          int flat = t + (r << 8);
          int m = flat >> 2, k8 = (flat & 3) << 3;
          async16(arow + m * 256 + k0 + k8, &a_lds[h][flat << 3]);
        }
#pragma unroll
        for (int r = 0; r < 2; ++r) {
          int flat = t + (r << 8);
          int n = flat >> 2, k8 = (flat & 3) << 3;
          async16(wt + (size_t)(n0 + n) * 2304 + tap * 256 + k0 + k8, &b_lds[h][flat << 3]);
        }
      }
      __syncthreads();
#pragma unroll
      for (int h = 0; h < 2; ++h) {
        short8 af[4], bfr[4];
#pragma unroll
        for (int i = 0; i < 4; ++i) {
          af[i]  = *(const short8*)&a_lds[h][((wm << 6) + (i << 4) + (lane & 15)) * 32 + ((lane >> 4) << 3)];
          bfr[i] = *(const short8*)&b_lds[h][((wn << 6) + (i << 4) + (lane & 15)) * 32 + ((lane >> 4) << 3)];
        }
#pragma unroll
        for (int i = 0; i < 4; ++i) {
#pragma unroll
          for (int j = 0; j < 4; ++j)
            acc[i][j] = __builtin_amdgcn_mfma_f32_16x16x32_bf16(af[i], bfr[j], acc[i][j], 0, 0, 0);
        }
      }
      __syncthreads();
    }
  }

  int prow = rb << 7;
#pragma unroll
  for (int j = 0; j < 4; ++j) {
    int o = n0 + (wn << 6) + (j << 4) + (lane & 15);
    float dv = dmod[(b << 8) + o];
    float bv = bias[o];
    float nc = ncoef[o];
#pragma unroll
    for (int i = 0; i < 4; ++i) {
      int mbase = (wm << 6) + (i << 4) + ((lane >> 4) << 2);
#pragma unroll
      for (int r = 0; r < 4; ++r) {
        int idx = (prow + mbase + r) * 256 + o;
        float v = acc[i][j][r] * dv + bv + noise[idx] * nc;
        y[idx] = f2bf(lrelu(v));
      }
    }
  }
}

// ---------------- fused D1+D2: reads y (bf16, ws), writes final out (f32, d_out) ----------------
// GEMM1 now BK=64 as two [128][32] half-tiles: barrier pairs per nc 8 -> 4.
__global__ __launch_bounds__(256, 2) void k_dense(
    const ushort_t* __restrict__ y, float* __restrict__ out,
    const ushort_t* __restrict__ w1t, const float* __restrict__ b1,
    const ushort_t* __restrict__ w2t, const float* __restrict__ b2) {
  __shared__ __align__(16) ushort_t a1[2][128 * 32];   // y tile halves [m][k]
  __shared__ __align__(16) ushort_t bb[256 * 32];      // GEMM1: two 128x32 halves / GEMM2: [o][k]
  __shared__ __align__(16) ushort_t ly[128 * 136];     // h tile [m][k], padded row (+8)
  int rb = blockIdx.x;
  int t = threadIdx.x, lane = t & 63;
  int wm = (t >> 7) & 1, wn = (t >> 6) & 1;
  int row0 = rb << 7;

  const f32x4 fz = {0.f, 0.f, 0.f, 0.f};
  f32x4 oacc[4][8];
#pragma unroll
  for (int i = 0; i < 4; ++i) {
#pragma unroll
    for (int j = 0; j < 8; ++j) oacc[i][j] = fz;
  }

#pragma unroll 1
  for (int nc = 0; nc < 8; ++nc) {
    f32x4 hacc[4][4];
#pragma unroll
    for (int i = 0; i < 4; ++i) {
#pragma unroll
      for (int j = 0; j < 4; ++j) hacc[i][j] = fz;
    }
    // GEMM1: h_chunk[128 x 128] = y[128 x 256] @ W1s[:, nc*128 .. ]
#pragma unroll 1
    for (int kp = 0; kp < 4; ++kp) {
#pragma unroll
      for (int h = 0; h < 2; ++h) {
        int k0 = ((kp << 1) + h) << 5;
#pragma unroll
        for (int r = 0; r < 2; ++r) {
          int flat = t + (r << 8);
          int m = flat >> 2, k8 = (flat & 3) << 3;
          async16(y + (row0 + m) * 256 + k0 + k8, &a1[h][flat << 3]);
          async16(w1t + ((nc << 7) + m) * 256 + k0 + k8, &bb[(h << 12) + (flat << 3)]);
        }
      }
      __syncthreads();
#pragma unroll
      for (int h = 0; h < 2; ++h) {
        short8 af[4], bfr[4];
#pragma unroll
        for (int i = 0; i < 4; ++i) {
          af[i]  = *(const short8*)&a1[h][((wm << 6) + (i << 4) + (lane & 15)) * 32 + ((lane >> 4) << 3)];
          bfr[i] = *(const short8*)&bb[(h << 12) + ((wn << 6) + (i << 4) + (lane & 15)) * 32 + ((lane >> 4) << 3)];
        }
#pragma unroll
        for (int i = 0; i < 4; ++i) {
#pragma unroll
          for (int j = 0; j < 4; ++j)
            hacc[i][j] = __builtin_amdgcn_mfma_f32_16x16x32_bf16(af[i], bfr[j], hacc[i][j], 0, 0, 0);
        }
      }
      __syncthreads();
    }
    // h = lrelu(hacc + b1) -> ly (bf16, A-operand layout for GEMM2)
#pragma unroll
    for (int j = 0; j < 4; ++j) {
      int n = (wn << 6) + (j << 4) + (lane & 15);
      float bv = b1[(nc << 7) + n];
#pragma unroll
      for (int i = 0; i < 4; ++i) {
        int mbase = (wm << 6) + (i << 4) + ((lane >> 4) << 2);
#pragma unroll
        for (int r = 0; r < 4; ++r)
          ly[(mbase + r) * 136 + n] = f2bf(lrelu(hacc[i][j][r] + bv));
      }
    }
    __syncthreads();
    // GEMM2: oacc += h_chunk[128 x 128] @ W2s[nc*128 .. , 0..256]
#pragma unroll 1
    for (int kc2 = 0; kc2 < 4; ++kc2) {
      int kk0 = kc2 << 5;
#pragma unroll
      for (int r = 0; r < 4; ++r) {
        int flat = t + (r << 8);
        int o = flat >> 2, k8 = (flat & 3) << 3;
        async16(w2t + o * 1024 + (nc << 7) + kk0 + k8, &bb[flat << 3]);
      }
      __syncthreads();
      short8 af2[4];
#pragma unroll
      for (int i = 0; i < 4; ++i)
        af2[i] = *(const short8*)&ly[((wm << 6) + (i << 4) + (lane & 15)) * 136 + kk0 + ((lane >> 4) << 3)];
#pragma unroll
      for (int j = 0; j < 8; ++j) {
        short8 bfr2 = *(const short8*)&bb[((wn << 7) + (j << 4) + (lane & 15)) * 32 + ((lane >> 4) << 3)];
#pragma unroll
        for (int i = 0; i < 4; ++i)
          oacc[i][j] = __builtin_amdgcn_mfma_f32_16x16x32_bf16(af2[i], bfr2, oacc[i][j], 0, 0, 0);
      }
      __syncthreads();
    }
  }
  // epilogue: out = lrelu(oacc + b2)  (f32)
#pragma unroll
  for (int j = 0; j < 8; ++j) {
    int o = (wn << 7) + (j << 4) + (lane & 15);
    float bv = b2[o];
#pragma unroll
    for (int i = 0; i < 4; ++i) {
      int mbase = (wm << 6) + (i << 4) + ((lane >> 4) << 2);
#pragma unroll
      for (int r = 0; r < 4; ++r)
        out[(row0 + mbase + r) * 256 + o] = lrelu(oacc[i][j][r] + bv);
    }
  }
}

extern "C" void kernel_launch(void* const* d_in, const int* in_sizes, int n_in,
                              void* d_out, int out_size, void* d_ws, size_t ws_size,
                              hipStream_t stream) {
  const float* data   = (const float*)d_in[0];
  const float* latent = (const float*)d_in[1];
  const float* noise  = (const float*)d_in[2];
  const float* stdW   = (const float*)d_in[3];
  const float* stdb   = (const float*)d_in[4];
  const float* convw  = (const float*)d_in[5];
  const float* bias   = (const float*)d_in[6];
  const float* ncoef  = (const float*)d_in[7];
  const float* D1W    = (const float*)d_in[8];
  const float* D1b    = (const float*)d_in[9];
  const float* D2W    = (const float*)d_in[10];
  const float* D2b    = (const float*)d_in[11];
  float* out = (float*)d_out;

  char* ws = (char*)d_ws;
  float*    s    = (float*)ws;                       //      8 KB
  float*    dmod = (float*)(ws + 8192);              //      8 KB
  float*    w2   = (float*)(ws + 16384);             //    256 KB
  ushort_t* wt   = (ushort_t*)(ws + 278528);         //  1,179,648 B  wt[o][2304]
  ushort_t* w1t  = (ushort_t*)(ws + 1458176);        //    512 KB  w1t[n][256]
  ushort_t* w2t  = (ushort_t*)(ws + 1982464);        //    512 KB  w2t[o][1024]
  ushort_t* xs   = (ushort_t*)(ws + 2506752);        //  69,222,400 B  xs[8][130][130][256]
  ushort_t* yv   = (ushort_t*)(ws + 71729152);       //  67,108,864 B  y[8*128*128][256]
                                                     //  total ~139 MB

  k_style<<<dim3(8, 8), 256, 0, stream>>>(latent, stdW, stdb, s);
  k_w2<<<256, 256, 0, stream>>>(convw, w2);
  k_demod<<<dim3(8, 8), 256, 0, stream>>>(w2, s, dmod);
  k_wt<<<2304, 256, 0, stream>>>(convw, wt);
  k_w1t<<<1024, 256, 0, stream>>>(D1W, w1t);
  k_w2t<<<1024, 256, 0, stream>>>(D2W, w2t);
  k_pad<<<16900, 256, 0, stream>>>(data, s, xs);     // 16900*256 threads = 8*130*130*32 exactly
  k_conv<<<dim3(1024, 2), 256, 0, stream>>>(xs, wt, dmod, bias, ncoef, noise, yv);
  k_dense<<<1024, 256, 0, stream>>>(yv, out, w1t, D1b, w2t, D2b);
}

// Round 2
// 703.496 us; speedup vs baseline: 1.1309x; 1.1309x over previous
//
#include <hip/hip_runtime.h>

typedef unsigned short ushort_t;
typedef __attribute__((ext_vector_type(8))) short short8;   // 8 bf16 (4 VGPRs)
typedef __attribute__((ext_vector_type(4))) float f32x4;

#define C1 0.0625f                      // sqrt(2/512)
#define C2 0.029462782549439483f        // sqrt(2/2304)
#define C2SQ (2.0f/2304.0f)
#define C3 0.08838834764831845f         // sqrt(2/256)
#define C4 0.04419417382415922f         // sqrt(2/1024)

__device__ __forceinline__ float bf2f(ushort_t u) {
  union { unsigned int i; float f; } v; v.i = ((unsigned int)u) << 16; return v.f;
}
__device__ __forceinline__ ushort_t f2bf(float f) {
  union { float f; unsigned int i; } v; v.f = f;
  unsigned int r = v.i + 0x7fffu + ((v.i >> 16) & 1u);   // RNE
  return (ushort_t)(r >> 16);
}
__device__ __forceinline__ void async16(const void* g, void* l) {
  __builtin_amdgcn_global_load_lds(
      (const __attribute__((address_space(1))) unsigned int*)g,
      (__attribute__((address_space(3))) unsigned int*)l, 16, 0, 0);
}
__device__ __forceinline__ float lrelu(float v) { return v > 0.f ? v : 0.2f * v; }

// ---------------- prep: style vector s[b][i] (f32 in, f32 out) ----------------
__global__ void k_style(const float* __restrict__ latent, const float* __restrict__ stdW,
                        const float* __restrict__ stdb, float* __restrict__ s) {
  __shared__ float red[256];
  int b = blockIdx.x, ic = blockIdx.y;
  int il = threadIdx.x & 31, lp = threadIdx.x >> 5;
  int i = (ic << 5) + il;
  float acc = 0.f;
  int l0 = lp << 6;
  for (int l = l0; l < l0 + 64; ++l)
    acc += latent[(b << 9) + l] * stdW[(l << 8) + i];
  red[threadIdx.x] = acc;
  __syncthreads();
  if (lp == 0) {
    float v = 0.f;
#pragma unroll
    for (int p = 0; p < 8; ++p) v += red[(p << 5) + il];
    s[(b << 8) + i] = v * C1 + stdb[i];
  }
}

// ---------------- prep: w2[i][o] = c2^2 * sum_tap w^2 ----------------
__global__ void k_w2(const float* __restrict__ convw, float* __restrict__ w2) {
  int t = blockIdx.x * 256 + threadIdx.x;      // i*256+o
  float acc = 0.f;
#pragma unroll
  for (int tap = 0; tap < 9; ++tap) {
    float w = convw[tap * 65536 + t];
    acc += w * w;
  }
  w2[t] = acc * C2SQ;
}

// ---------------- prep: demod d[b][o] ----------------
__global__ void k_demod(const float* __restrict__ w2, const float* __restrict__ s,
                        float* __restrict__ dm) {
  __shared__ float red[256];
  int b = blockIdx.x, oc = blockIdx.y;
  int ol = threadIdx.x & 31, ip = threadIdx.x >> 5;
  int o = (oc << 5) + ol;
  float acc = 0.f;
  int i0 = ip << 5;
  for (int i = i0; i < i0 + 32; ++i) {
    float si = s[(b << 8) + i];
    acc += w2[(i << 8) + o] * si * si;
  }
  red[threadIdx.x] = acc;
  __syncthreads();
  if (ip == 0) {
    float v = 1e-8f;
#pragma unroll
    for (int p = 0; p < 8; ++p) v += red[(p << 5) + ol];
    dm[(b << 8) + o] = rsqrtf(v);
  }
}

// ---------------- prep: conv weights transposed+scaled wt[o][tap*256+i] (bf16) ----------------
__global__ void k_wt(const float* __restrict__ convw, ushort_t* __restrict__ wt) {
  int t = blockIdx.x * 256 + threadIdx.x;      // o*2304 + kk (write-coalesced)
  int o = t / 2304;
  int kk = t - o * 2304;
  int tap = kk >> 8, i = kk & 255;
  wt[t] = f2bf(convw[tap * 65536 + (i << 8) + o] * C2);
}

// ---------------- prep: W1t[n][k] = D1_W[k][n]*c3 ; W2t[o][k] = D2_W[k][o]*c4 (bf16) ----------------
__global__ void k_w1t(const float* __restrict__ d1w, ushort_t* __restrict__ w1t) {
  int t = blockIdx.x * 256 + threadIdx.x;      // n*256 + k
  int n = t >> 8, k = t & 255;
  w1t[t] = f2bf(d1w[(k << 10) + n] * C3);
}
__global__ void k_w2t(const float* __restrict__ d2w, ushort_t* __restrict__ w2t) {
  int t = blockIdx.x * 256 + threadIdx.x;      // o*1024 + k
  int o = t >> 10, k = t & 1023;
  w2t[t] = f2bf(d2w[(k << 8) + o] * C4);
}

// ---------------- prep: modulated + zero-padded input xs[8][130][130][256] (bf16) ----------------
__global__ void k_pad(const float* __restrict__ data, const float* __restrict__ s,
                      ushort_t* __restrict__ xs) {
  int tid = blockIdx.x * 256 + threadIdx.x;    // one thread = 8 channels
  int ci8 = tid & 31;
  int p = tid >> 5;                            // b*130*130 + yp*130 + xp
  int xp = p % 130;
  int q = p / 130;
  int yp = q % 130;
  int b = q / 130;
  short8 ov = {0, 0, 0, 0, 0, 0, 0, 0};
  if (yp >= 1 && yp <= 128 && xp >= 1 && xp <= 128) {
    const f32x4* src = (const f32x4*)(data + ((((b << 7) + (yp - 1)) << 7) + (xp - 1)) * 256 + (ci8 << 3));
    const f32x4* sp  = (const f32x4*)(s + (b << 8) + (ci8 << 3));
    f32x4 v0 = src[0], v1 = src[1];
    f32x4 s0 = sp[0],  s1 = sp[1];
#pragma unroll
    for (int j = 0; j < 4; ++j) ov[j]     = (short)f2bf(v0[j] * s0[j]);
#pragma unroll
    for (int j = 0; j < 4; ++j) ov[4 + j] = (short)f2bf(v1[j] * s1[j]);
  }
  *(short8*)(xs + ((size_t)tid << 3)) = ov;
}

// ================= conv3x3 implicit GEMM — 256x256 tile, 8-phase counted-vmcnt =================
// BM=BN=256, BK=64, 512 thr (8 waves, 2M x 4N), LDS 2 bufs x {A0,A1,B0,B1} halves = 128 KB.
// Phase (mh,nh) reads ONLY A-half mh + B-half nh (wave rows = mh*128+wm*64+.., cols = nh*128+wn*32+..)
// -> half-granular pipeline with 2 buffers. Stage order per tile: P0->A0', P1->B0', P2->B1', P3->A1'.
// FIFO waits: vmcnt(4) at P0/P1/P2 (drains exactly the 2 loads that phase needs), none at P3.
// T2 swizzle byte ^= (row&7)<<4 via inverse-swizzled GLOBAL source (linear LDS dest, rule #21).

#define SWZ_FLAT(flat, row) ((((flat) ^ (row)) & 7) << 3)   // swizzled k-chunk (in elements)

__device__ __forceinline__ void stage_a(const ushort_t* ximg, int y0, int h, int kt2,
                                        int t, ushort_t* dst) {
  int tap = kt2 >> 2;
  int ci0 = (kt2 & 3) << 6;
  int ky = (tap >= 6) ? 2 : (tap >= 3 ? 1 : 0);
  int kx = tap - ky * 3;
  const ushort_t* ga = ximg + ((y0 + h + ky) * 130 + kx) * 256 + ci0;
#pragma unroll
  for (int is = 0; is < 2; ++is) {
    int flat = t + (is << 9);
    int row = flat >> 3;                       // row == x (one image row per half)
    int cil = SWZ_FLAT(flat, row);
    async16(ga + row * 256 + cil, dst + (flat << 3));
  }
}

__device__ __forceinline__ void stage_b(const ushort_t* wtp, int h, int kt2, int t, ushort_t* dst) {
  const ushort_t* gb = wtp + (kt2 << 6) + (size_t)(h << 7) * 2304;
#pragma unroll
  for (int is = 0; is < 2; ++is) {
    int flat = t + (is << 9);
    int row = flat >> 3;                       // local n
    int cil = SWZ_FLAT(flat, row);
    async16(gb + (size_t)row * 2304 + cil, dst + (flat << 3));
  }
}

#define LOAD_A(BASE) {                                                        \
  _Pragma("unroll") for (int q = 0; q < 4; ++q) {                             \
    int lr = (wm << 6) + (q << 4) + (lane & 15);                              \
    int bo0 = (lr << 7) + ((lane >> 4) << 4);                                 \
    int sw = (lr & 7) << 4;                                                   \
    af[q][0] = *(const short8*)((BASE) + ((bo0      ) ^ sw));                 \
    af[q][1] = *(const short8*)((BASE) + ((bo0 + 64 ) ^ sw)); } }

#define LOAD_B(BASE, BF) {                                                    \
  _Pragma("unroll") for (int p = 0; p < 2; ++p) {                             \
    int lr = (wn << 5) + (p << 4) + (lane & 15);                              \
    int bo0 = (lr << 7) + ((lane >> 4) << 4);                                 \
    int sw = (lr & 7) << 4;                                                   \
    BF[p][0] = *(const short8*)((BASE) + ((bo0      ) ^ sw));                 \
    BF[p][1] = *(const short8*)((BASE) + ((bo0 + 64 ) ^ sw)); } }

#define MFMA_BLK(MH, NH, BF) {                                                \
  _Pragma("unroll") for (int q = 0; q < 4; ++q)                               \
    _Pragma("unroll") for (int p = 0; p < 2; ++p)                             \
      _Pragma("unroll") for (int ks = 0; ks < 2; ++ks)                        \
        acc[MH][NH][q][p] = __builtin_amdgcn_mfma_f32_16x16x32_bf16(          \
            af[q][ks], BF[p][ks], acc[MH][NH][q][p], 0, 0, 0); }

#define PH_BAR()  __builtin_amdgcn_s_barrier()
#define PH_LGKM() asm volatile("s_waitcnt lgkmcnt(0)" ::: "memory")
#define VM4()     asm volatile("s_waitcnt vmcnt(4)" ::: "memory")
#define PRIO1()   __builtin_amdgcn_s_setprio(1)
#define PRIO0()   __builtin_amdgcn_s_setprio(0)

__global__ __launch_bounds__(512, 2) void k_conv(
    const ushort_t* __restrict__ xs, const ushort_t* __restrict__ wt,
    const float* __restrict__ dmod, const float* __restrict__ bias,
    const float* __restrict__ ncoef, const float* __restrict__ noise,
    ushort_t* __restrict__ y) {
  __shared__ __align__(16) ushort_t lds[2][4][128 * 64];   // [buf][A0,A1,B0,B1][row*64+k]

  int bid0 = blockIdx.x;
  int bid = (bid0 & 7) * 64 + (bid0 >> 3);     // XCD swizzle (512 % 8 == 0, bijective)
  int m0 = bid << 8;
  int b = m0 >> 14;
  int y0 = (m0 & 16383) >> 7;                  // first of two image rows
  const ushort_t* ximg = xs + (size_t)b * (130 * 130 * 256);

  int t = threadIdx.x;
  int lane = t & 63;
  int wid = t >> 6;
  int wm = wid >> 2, wn = wid & 3;             // 2M x 4N waves

  const f32x4 fz = {0.f, 0.f, 0.f, 0.f};
  f32x4 acc[2][2][4][2];                       // [mh][nh][q][p]
#pragma unroll
  for (int a0 = 0; a0 < 2; ++a0)
#pragma unroll
    for (int a1 = 0; a1 < 2; ++a1)
#pragma unroll
      for (int a2 = 0; a2 < 4; ++a2)
#pragma unroll
        for (int a3 = 0; a3 < 2; ++a3) acc[a0][a1][a2][a3] = fz;

  short8 af[4][2], bf[2][2], bg[2][2];

  // prologue: stage tile 0 in FIFO order A0, B0, B1, A1  (8 loads outstanding)
  stage_a(ximg, y0, 0, 0, t, &lds[0][0][0]);
  stage_b(wt,        0, 0, t, &lds[0][2][0]);
  stage_b(wt,        1, 0, t, &lds[0][3][0]);
  stage_a(ximg, y0, 1, 0, t, &lds[0][1][0]);

#pragma unroll 1
  for (int kt = 0; kt < 35; ++kt) {
    int cb = kt & 1, nb = cb ^ 1;
    const char* a0b = (const char*)&lds[cb][0][0];
    const char* a1b = (const char*)&lds[cb][1][0];
    const char* b0b = (const char*)&lds[cb][2][0];
    const char* b1b = (const char*)&lds[cb][3][0];
    int kt2 = kt + 1;
    // P0 (mh0,nh0): needs A0,B0 of kt -> drained by vmcnt(4)
    VM4(); PH_BAR();
    LOAD_A(a0b); LOAD_B(b0b, bf);
    stage_a(ximg, y0, 0, kt2, t, &lds[nb][0][0]);
    PH_BAR(); PH_LGKM();
    PRIO1(); MFMA_BLK(0, 0, bf); PRIO0();
    // P1 (mh0,nh1): needs B1 of kt
    VM4(); PH_BAR();
    LOAD_B(b1b, bg);
    stage_b(wt, 0, kt2, t, &lds[nb][2][0]);
    PH_BAR(); PH_LGKM();
    PRIO1(); MFMA_BLK(0, 1, bg); PRIO0();
    // P2 (mh1,nh1): needs A1 of kt
    VM4(); PH_BAR();
    LOAD_A(a1b);
    stage_b(wt, 1, kt2, t, &lds[nb][3][0]);
    PH_BAR(); PH_LGKM();
    PRIO1(); MFMA_BLK(1, 1, bg); PRIO0();
    // P3 (mh1,nh0): registers only
    stage_a(ximg, y0, 1, kt2, t, &lds[nb][1][0]);
    PH_BAR();
    PRIO1(); MFMA_BLK(1, 0, bf); PRIO0();
  }
  // peeled last tile (kt=35, buffer 1, no staging): drain 8 -> 4 -> 2 -> 0
  {
    const char* a0b = (const char*)&lds[1][0][0];
    const char* a1b = (const char*)&lds[1][1][0];
    const char* b0b = (const char*)&lds[1][2][0];
    const char* b1b = (const char*)&lds[1][3][0];
    asm volatile("s_waitcnt vmcnt(4)" ::: "memory"); PH_BAR();
    LOAD_A(a0b); LOAD_B(b0b, bf);
    PH_BAR(); PH_LGKM();
    PRIO1(); MFMA_BLK(0, 0, bf); PRIO0();
    asm volatile("s_waitcnt vmcnt(2)" ::: "memory"); PH_BAR();
    LOAD_B(b1b, bg);
    PH_BAR(); PH_LGKM();
    PRIO1(); MFMA_BLK(0, 1, bg); PRIO0();
    asm volatile("s_waitcnt vmcnt(0)" ::: "memory"); PH_BAR();
    LOAD_A(a1b);
    PH_BAR(); PH_LGKM();
    PRIO1(); MFMA_BLK(1, 1, bg); PRIO0();
    PH_BAR();
    PRIO1(); MFMA_BLK(1, 0, bf); PRIO0();
  }

  // epilogue: demod + bias + noise + lrelu -> y (bf16)
#pragma unroll
  for (int mh = 0; mh < 2; ++mh)
#pragma unroll
    for (int nh = 0; nh < 2; ++nh)
#pragma unroll
      for (int p = 0; p < 2; ++p) {
        int o = (nh << 7) + (wn << 5) + (p << 4) + (lane & 15);
        float dv = dmod[(b << 8) + o];
        float bv = bias[o];
        float nc = ncoef[o];
#pragma unroll
        for (int q = 0; q < 4; ++q) {
          int mloc = (mh << 7) + (wm << 6) + (q << 4) + ((lane >> 4) << 2);
#pragma unroll
          for (int r = 0; r < 4; ++r) {
            int idx = (m0 + mloc + r) * 256 + o;
            float v = acc[mh][nh][q][p][r] * dv + bv + noise[idx] * nc;
            y[idx] = f2bf(lrelu(v));
          }
        }
      }
}

// ---------------- fused D1+D2: reads y (bf16, ws), writes final out (f32, d_out) ----------------
__global__ __launch_bounds__(256, 2) void k_dense(
    const ushort_t* __restrict__ y, float* __restrict__ out,
    const ushort_t* __restrict__ w1t, const float* __restrict__ b1,
    const ushort_t* __restrict__ w2t, const float* __restrict__ b2) {
  __shared__ __align__(16) ushort_t a1[2][128 * 32];   // y tile halves [m][k]
  __shared__ __align__(16) ushort_t bb[256 * 32];      // GEMM1: two 128x32 halves / GEMM2: [o][k]
  __shared__ __align__(16) ushort_t ly[128 * 136];     // h tile [m][k], padded row (+8)
  int rb = blockIdx.x;
  int t = threadIdx.x, lane = t & 63;
  int wm = (t >> 7) & 1, wn = (t >> 6) & 1;
  int row0 = rb << 7;

  const f32x4 fz = {0.f, 0.f, 0.f, 0.f};
  f32x4 oacc[4][8];
#pragma unroll
  for (int i = 0; i < 4; ++i) {
#pragma unroll
    for (int j = 0; j < 8; ++j) oacc[i][j] = fz;
  }

#pragma unroll 1
  for (int nc = 0; nc < 8; ++nc) {
    f32x4 hacc[4][4];
#pragma unroll
    for (int i = 0; i < 4; ++i) {
#pragma unroll
      for (int j = 0; j < 4; ++j) hacc[i][j] = fz;
    }
    // GEMM1: h_chunk[128 x 128] = y[128 x 256] @ W1s[:, nc*128 .. ]
#pragma unroll 1
    for (int kp = 0; kp < 4; ++kp) {
#pragma unroll
      for (int h = 0; h < 2; ++h) {
        int k0 = ((kp << 1) + h) << 5;
#pragma unroll
        for (int r = 0; r < 2; ++r) {
          int flat = t + (r << 8);
          int m = flat >> 2, k8 = (flat & 3) << 3;
          async16(y + (row0 + m) * 256 + k0 + k8, &a1[h][flat << 3]);
          async16(w1t + ((nc << 7) + m) * 256 + k0 + k8, &bb[(h << 12) + (flat << 3)]);
        }
      }
      __syncthreads();
#pragma unroll
      for (int h = 0; h < 2; ++h) {
        short8 af[4], bfr[4];
#pragma unroll
        for (int i = 0; i < 4; ++i) {
          af[i]  = *(const short8*)&a1[h][((wm << 6) + (i << 4) + (lane & 15)) * 32 + ((lane >> 4) << 3)];
          bfr[i] = *(const short8*)&bb[(h << 12) + ((wn << 6) + (i << 4) + (lane & 15)) * 32 + ((lane >> 4) << 3)];
        }
#pragma unroll
        for (int i = 0; i < 4; ++i) {
#pragma unroll
          for (int j = 0; j < 4; ++j)
            hacc[i][j] = __builtin_amdgcn_mfma_f32_16x16x32_bf16(af[i], bfr[j], hacc[i][j], 0, 0, 0);
        }
      }
      __syncthreads();
    }
    // h = lrelu(hacc + b1) -> ly (bf16, A-operand layout for GEMM2)
#pragma unroll
    for (int j = 0; j < 4; ++j) {
      int n = (wn << 6) + (j << 4) + (lane & 15);
      float bv = b1[(nc << 7) + n];
#pragma unroll
      for (int i = 0; i < 4; ++i) {
        int mbase = (wm << 6) + (i << 4) + ((lane >> 4) << 2);
#pragma unroll
        for (int r = 0; r < 4; ++r)
          ly[(mbase + r) * 136 + n] = f2bf(lrelu(hacc[i][j][r] + bv));
      }
    }
    __syncthreads();
    // GEMM2: oacc += h_chunk[128 x 128] @ W2s[nc*128 .. , 0..256]
#pragma unroll 1
    for (int kc2 = 0; kc2 < 4; ++kc2) {
      int kk0 = kc2 << 5;
#pragma unroll
      for (int r = 0; r < 4; ++r) {
        int flat = t + (r << 8);
        int o = flat >> 2, k8 = (flat & 3) << 3;
        async16(w2t + o * 1024 + (nc << 7) + kk0 + k8, &bb[flat << 3]);
      }
      __syncthreads();
      short8 af2[4];
#pragma unroll
      for (int i = 0; i < 4; ++i)
        af2[i] = *(const short8*)&ly[((wm << 6) + (i << 4) + (lane & 15)) * 136 + kk0 + ((lane >> 4) << 3)];
#pragma unroll
      for (int j = 0; j < 8; ++j) {
        short8 bfr2 = *(const short8*)&bb[((wn << 7) + (j << 4) + (lane & 15)) * 32 + ((lane >> 4) << 3)];
#pragma unroll
        for (int i = 0; i < 4; ++i)
          oacc[i][j] = __builtin_amdgcn_mfma_f32_16x16x32_bf16(af2[i], bfr2, oacc[i][j], 0, 0, 0);
      }
      __syncthreads();
    }
  }
  // epilogue: out = lrelu(oacc + b2)  (f32)
#pragma unroll
  for (int j = 0; j < 8; ++j) {
    int o = (wn << 7) + (j << 4) + (lane & 15);
    float bv = b2[o];
#pragma unroll
    for (int i = 0; i < 4; ++i) {
      int mbase = (wm << 6) + (i << 4) + ((lane >> 4) << 2);
#pragma unroll
      for (int r = 0; r < 4; ++r)
        out[(row0 + mbase + r) * 256 + o] = lrelu(oacc[i][j][r] + bv);
    }
  }
}

extern "C" void kernel_launch(void* const* d_in, const int* in_sizes, int n_in,
                              void* d_out, int out_size, void* d_ws, size_t ws_size,
                              hipStream_t stream) {
  const float* data   = (const float*)d_in[0];
  const float* latent = (const float*)d_in[1];
  const float* noise  = (const float*)d_in[2];
  const float* stdW   = (const float*)d_in[3];
  const float* stdb   = (const float*)d_in[4];
  const float* convw  = (const float*)d_in[5];
  const float* bias   = (const float*)d_in[6];
  const float* ncoef  = (const float*)d_in[7];
  const float* D1W    = (const float*)d_in[8];
  const float* D1b    = (const float*)d_in[9];
  const float* D2W    = (const float*)d_in[10];
  const float* D2b    = (const float*)d_in[11];
  float* out = (float*)d_out;

  char* ws = (char*)d_ws;
  float*    s    = (float*)ws;                       //      8 KB
  float*    dmod = (float*)(ws + 8192);              //      8 KB
  float*    w2   = (float*)(ws + 16384);             //    256 KB
  ushort_t* wt   = (ushort_t*)(ws + 278528);         //  1,179,648 B  wt[o][2304]
  ushort_t* w1t  = (ushort_t*)(ws + 1458176);        //    512 KB  w1t[n][256]
  ushort_t* w2t  = (ushort_t*)(ws + 1982464);        //    512 KB  w2t[o][1024]
  ushort_t* xs   = (ushort_t*)(ws + 2506752);        //  69,222,400 B  xs[8][130][130][256]
  ushort_t* yv   = (ushort_t*)(ws + 71729152);       //  67,108,864 B  y[8*128*128][256]
                                                     //  total ~139 MB

  k_style<<<dim3(8, 8), 256, 0, stream>>>(latent, stdW, stdb, s);
  k_w2<<<256, 256, 0, stream>>>(convw, w2);
  k_demod<<<dim3(8, 8), 256, 0, stream>>>(w2, s, dmod);
  k_wt<<<2304, 256, 0, stream>>>(convw, wt);
  k_w1t<<<1024, 256, 0, stream>>>(D1W, w1t);
  k_w2t<<<1024, 256, 0, stream>>>(D2W, w2t);
  k_pad<<<16900, 256, 0, stream>>>(data, s, xs);     // 16900*256 threads = 8*130*130*32 exactly
  k_conv<<<512, 512, 0, stream>>>(xs, wt, dmod, bias, ncoef, noise, yv);
  k_dense<<<1024, 256, 0, stream>>>(yv, out, w1t, D1b, w2t, D2b);
}